// Round 5
// baseline (483.480 us; speedup 1.0000x reference)
//
#include <hip/hip_runtime.h>
#include <hip/hip_bf16.h>
#include <cmath>

#define HD 512
#define ND 2048
#define NB 32
#define NT 128   // n-rows per workgroup (8 waves x 64 output cols each)

typedef _Float16 half8 __attribute__((ext_vector_type(8)));
typedef float f32x4 __attribute__((ext_vector_type(4)));

// Bank-uniform LDS layout: 16B slot for (row n, k-block kb) at
//   n*1024B + ((kb ^ q(n)) * 16B),  q(n) = (n ^ (n>>2)) & 7.
// q() is GF(2)-linear and surjective on both {16 consecutive n} (A-frag read
// phases) and {n = j+4m} (transpose write phases) -> conflict-free both ways.
__device__ __forceinline__ int qf(int n) { return (n ^ (n >> 2)) & 7; }
__device__ __forceinline__ int xslot(int n, int kb) {
  return (n << 9) + ((kb ^ qf(n)) << 3);
}

// One K=512 GEMM stage: D[128 rows][64 cols per wave] += X(128x512,f16,LDS) * Wg^T
// Wg row-major [outdim][512] fp16, offset to this wave's 64-row slice.
// mt-outer: only 1 A-frag live at a time -> no spill at 128 AGPR acc.
__device__ __forceinline__ void mfma_stage(const _Float16* Xs,
                                           const _Float16* __restrict__ Wg,
                                           f32x4 (&acc)[8][4], int c, int qw) {
  const _Float16* wb = Wg + (size_t)c * HD + qw * 8;
  int rowoff[8], qn[8];
#pragma unroll
  for (int mt = 0; mt < 8; ++mt) {
    int n = mt * 16 + c;
    rowoff[mt] = n << 9;
    qn[mt] = qf(n);
  }
#pragma unroll 2
  for (int ks = 0; ks < 16; ++ks) {
    int k8 = ks * 4 + qw;
    half8 bf[4];
#pragma unroll
    for (int ht = 0; ht < 4; ++ht)
      bf[ht] = *(const half8*)(wb + ht * (16 * HD) + ks * 32);
#pragma unroll
    for (int mt = 0; mt < 8; ++mt) {
      half8 a = *(const half8*)&Xs[rowoff[mt] + ((k8 ^ qn[mt]) << 3)];
#pragma unroll
      for (int ht = 0; ht < 4; ++ht)
        acc[mt][ht] = __builtin_amdgcn_mfma_f32_16x16x32_f16(a, bf[ht], acc[mt][ht], 0, 0, 0);
    }
  }
}

// K2: blocks 0..31: pm[b] + b1[b] (folded bias). 32..95: Wc216 cvt. 96..159: WkbT16.
__global__ __launch_bounds__(256) void prep_k(
    const float* __restrict__ memory, const float* __restrict__ masks,
    const float* __restrict__ W_mem, const float* __restrict__ b_mem,
    const float* __restrict__ W_kb, const float* __restrict__ b_kb,
    const float* __restrict__ W_cat, const float* __restrict__ b_cat,
    const float* __restrict__ W_cat2,
    float* __restrict__ pm, float* __restrict__ b1,
    _Float16* __restrict__ Wc216, _Float16* __restrict__ WkbT16) {
  const int tid = threadIdx.x;
  const int blk = blockIdx.x;
  if (blk < 32) {
    // pm[b][h] = (memory[3,b,:]*masks[b,:]).W_mem[h,:] + b_mem[h]
    // b1[b][h'] = W_cat[h',0:512].(pm_b*b_kb) + W_cat[h',512:1024].b_kb + b_cat[h']
    int b = blk;
    __shared__ float lm[HD], pm_s[HD], bkb[HD];
    for (int i = tid; i < HD; i += 256) {
      lm[i] = memory[(size_t)(3 * NB + b) * HD + i] * masks[(size_t)b * HD + i];
      bkb[i] = b_kb[i];
    }
    __syncthreads();
    for (int h = tid; h < HD; h += 256) {
      const f32x4* wr = (const f32x4*)(W_mem + (size_t)h * HD);
      const f32x4* lv = (const f32x4*)lm;
      float s = 0.f;
#pragma unroll 4
      for (int k = 0; k < 128; ++k) {
        f32x4 wv = wr[k]; f32x4 l = lv[k];
        s += wv[0]*l[0] + wv[1]*l[1] + wv[2]*l[2] + wv[3]*l[3];
      }
      s += b_mem[h];
      pm_s[h] = s;
      pm[(size_t)b * HD + h] = s;
    }
    __syncthreads();
    for (int i = tid; i < HD; i += 256) lm[i] = pm_s[i] * bkb[i];
    __syncthreads();
    for (int h = tid; h < HD; h += 256) {
      const f32x4* wa = (const f32x4*)(W_cat + (size_t)h * (2 * HD));
      const f32x4* wbp = (const f32x4*)(W_cat + (size_t)h * (2 * HD) + HD);
      const f32x4* yv = (const f32x4*)lm;
      const f32x4* bv = (const f32x4*)bkb;
      float s = 0.f;
#pragma unroll 4
      for (int k = 0; k < 128; ++k) {
        f32x4 a0 = wa[k], y = yv[k], a1 = wbp[k], z = bv[k];
        s += a0[0]*y[0] + a0[1]*y[1] + a0[2]*y[2] + a0[3]*y[3];
        s += a1[0]*z[0] + a1[1]*z[1] + a1[2]*z[2] + a1[3]*z[3];
      }
      b1[(size_t)b * HD + h] = s + b_cat[h];
    }
  } else if (blk < 96) {
    // Wc216: fp16 cvt of W_cat2, 8 rows per wg
    int r0 = (blk - 32) * 8;
    int r = r0 + (tid >> 5);
    int h0 = (tid & 31) * 16;
    const float* s = W_cat2 + (size_t)r * HD + h0;
    half8 o0, o1;
#pragma unroll
    for (int j = 0; j < 4; ++j) {
      o0[j] = (_Float16)s[j];       o0[4 + j] = (_Float16)s[4 + j];
      o1[j] = (_Float16)s[8 + j];   o1[4 + j] = (_Float16)s[12 + j];
    }
    *(half8*)(Wc216 + (size_t)r * HD + h0) = o0;
    *(half8*)(Wc216 + (size_t)r * HD + h0 + 8) = o1;
  } else {
    // WkbT16[j][h] = (fp16) W_kb[h][j], 8 j-rows per wg via LDS tile
    int j0 = (blk - 96) * 8;
    __shared__ float tr[HD][9];   // pad 9 to break bank stride
    for (int h = tid; h < HD; h += 256) {
      const float* s = W_kb + (size_t)h * HD + j0;
      f32x4 v0 = *(const f32x4*)s;
      f32x4 v1 = *(const f32x4*)(s + 4);
#pragma unroll
      for (int j = 0; j < 4; ++j) { tr[h][j] = v0[j]; tr[h][4 + j] = v1[j]; }
    }
    __syncthreads();
    int jj = tid >> 5;
    int h0 = (tid & 31) * 16;
    half8 o0, o1;
#pragma unroll
    for (int i = 0; i < 8; ++i) {
      o0[i] = (_Float16)tr[h0 + i][jj];
      o1[i] = (_Float16)tr[h0 + 8 + i][jj];
    }
    *(half8*)(WkbT16 + (size_t)(j0 + jj) * HD + h0) = o0;
    *(half8*)(WkbT16 + (size_t)(j0 + jj) * HD + h0 + 8) = o1;
  }
}

// K3: W1b[b] = Weff_b @ W_kb  (Weff_b built on the fly from W_cat & pm).
// Grid 128 = 32 b x 4 row-tiles. 8 waves, each 128 rows x 64 j-cols.
__global__ __launch_bounds__(512, 2) void w1gemm_k(
    const float* __restrict__ W_cat, const float* __restrict__ pm,
    const _Float16* __restrict__ WkbT16, _Float16* __restrict__ W1b16) {
  __shared__ _Float16 A[NT * HD];   // 128 KB
  const int tid = threadIdx.x;
  const int w = tid >> 6;
  const int lane = tid & 63;
  const int c = lane & 15;
  const int qw = lane >> 4;
  const int b = blockIdx.x >> 2;
  const int r0 = (blockIdx.x & 3) * NT;

  // stage A-tile: A[r][h] = (fp16)(pm[b][h]*W_cat[r0+r][h] + W_cat[r0+r][512+h])
  {
    const float* pmb = pm + (size_t)b * HD;
#pragma unroll 2
    for (int it = 0; it < 16; ++it) {
      int u = it * 512 + tid;
      int kb = u & 63;
      int r = u >> 6;
      const float* wc = W_cat + (size_t)(r0 + r) * (2 * HD) + kb * 8;
      f32x4 a0 = *(const f32x4*)wc;
      f32x4 a1 = *(const f32x4*)(wc + 4);
      f32x4 c0 = *(const f32x4*)(wc + HD);
      f32x4 c1 = *(const f32x4*)(wc + HD + 4);
      f32x4 p0 = *(const f32x4*)(pmb + kb * 8);
      f32x4 p1 = *(const f32x4*)(pmb + kb * 8 + 4);
      half8 hv;
#pragma unroll
      for (int j = 0; j < 4; ++j) {
        hv[j]     = (_Float16)(p0[j] * a0[j] + c0[j]);
        hv[4 + j] = (_Float16)(p1[j] * a1[j] + c1[j]);
      }
      *(half8*)&A[xslot(r, kb)] = hv;
    }
  }
  __syncthreads();

  f32x4 acc[8][4];
  const f32x4 z4 = {0.f, 0.f, 0.f, 0.f};
#pragma unroll
  for (int mt = 0; mt < 8; ++mt)
#pragma unroll
    for (int ht = 0; ht < 4; ++ht) acc[mt][ht] = z4;
  mfma_stage(A, WkbT16 + (size_t)(w * 64) * HD, acc, c, qw);

  // epilogue: W1b16[b][r0+row][col]
#pragma unroll
  for (int ht = 0; ht < 4; ++ht) {
    int col = w * 64 + ht * 16 + c;
#pragma unroll
    for (int mt = 0; mt < 8; ++mt)
#pragma unroll
      for (int r = 0; r < 4; ++r)
        W1b16[((size_t)b * HD + r0 + mt * 16 + qw * 4 + r) * HD + col] =
            (_Float16)acc[mt][ht][r];
  }
}

// K4: fused 2-stage chain + logits. XCD-swizzled grid: each b's 16 wgs on one XCD.
__global__ __launch_bounds__(512, 2) void main2_k(
    const float* __restrict__ know, const float* __restrict__ control,
    const _Float16* __restrict__ W1b16, const _Float16* __restrict__ Wc216,
    const float* __restrict__ b1, const float* __restrict__ b_cat2,
    const float* __restrict__ W_attn, float* __restrict__ logits) {
  __shared__ _Float16 X[NT * HD];   // 128 KB
  const int tid = threadIdx.x;
  const int w = tid >> 6;
  const int lane = tid & 63;
  const int c = lane & 15;
  const int qw = lane >> 4;
  const int gid = blockIdx.x;
  const int slot = gid >> 3;
  const int b = ((gid & 7) << 2) + (slot >> 4);   // 4 b per XCD -> W1b_b L2-resident
  const int n0 = (slot & 15) * NT;

  // stage 0: transpose know[b][k][n0+n] -> X (fp16), 8k x 4n register blocks,
  // full half8 (b128) LDS writes, conflict-free per qf() analysis.
  {
    const float* kptr = know + (size_t)b * HD * ND + n0;
#pragma unroll
    for (int it = 0; it < 4; ++it) {
      int u = it * 512 + tid;
      int n4 = (u & 31) << 2;
      int kb = u >> 5;
      int k0 = kb << 3;
      f32x4 v[8];
#pragma unroll
      for (int kk = 0; kk < 8; ++kk)
        v[kk] = *(const f32x4*)(kptr + (size_t)(k0 + kk) * ND + n4);
#pragma unroll
      for (int j = 0; j < 4; ++j) {
        int n = n4 + j;
        half8 hv;
#pragma unroll
        for (int kk = 0; kk < 8; ++kk) hv[kk] = (_Float16)v[kk][j];
        *(half8*)&X[xslot(n, kb)] = hv;
      }
    }
  }
  __syncthreads();

  f32x4 acc[8][4];
  const f32x4 z4 = {0.f, 0.f, 0.f, 0.f};

  // ---- stage A: h = elu(know_tile . W1b_b^T + b1_b)
#pragma unroll
  for (int mt = 0; mt < 8; ++mt)
#pragma unroll
    for (int ht = 0; ht < 4; ++ht) acc[mt][ht] = z4;
  mfma_stage(X, W1b16 + ((size_t)b * HD + w * 64) * HD, acc, c, qw);
  __syncthreads();
#pragma unroll
  for (int ht = 0; ht < 4; ++ht) {
    int col = w * 64 + ht * 16 + c;
    float bias = b1[(size_t)b * HD + col];
    int kb = col >> 3, k7 = col & 7;
#pragma unroll
    for (int mt = 0; mt < 8; ++mt)
#pragma unroll
      for (int r = 0; r < 4; ++r) {
        float v = acc[mt][ht][r] + bias;
        v = v > 0.f ? v : expm1f(v);
        int n = mt * 16 + qw * 4 + r;
        X[xslot(n, kb) + k7] = (_Float16)v;
      }
  }
  __syncthreads();

  // ---- stage B: h2 = h . Wc2^T + b_cat2; attn = elu(h2*ctl); logits = attn . W_attn
#pragma unroll
  for (int mt = 0; mt < 8; ++mt)
#pragma unroll
    for (int ht = 0; ht < 4; ++ht) acc[mt][ht] = z4;
  mfma_stage(X, Wc216 + (size_t)(w * 64) * HD, acc, c, qw);

  float ll[8][4];
#pragma unroll
  for (int mt = 0; mt < 8; ++mt)
#pragma unroll
    for (int r = 0; r < 4; ++r) ll[mt][r] = 0.f;
  const float* ctl = control + (size_t)(3 * NB + b) * HD;
#pragma unroll
  for (int ht = 0; ht < 4; ++ht) {
    int col = w * 64 + ht * 16 + c;
    float bias = b_cat2[col];
    float cv = ctl[col];
    float wa = W_attn[col];
#pragma unroll
    for (int mt = 0; mt < 8; ++mt)
#pragma unroll
      for (int r = 0; r < 4; ++r) {
        float h2 = acc[mt][ht][r] + bias;
        float at = h2 * cv;
        at = at > 0.f ? at : expm1f(at);
        ll[mt][r] += at * wa;
      }
  }
#pragma unroll
  for (int off = 1; off <= 8; off <<= 1)
#pragma unroll
    for (int mt = 0; mt < 8; ++mt)
#pragma unroll
      for (int r = 0; r < 4; ++r) ll[mt][r] += __shfl_xor(ll[mt][r], off);

  __syncthreads();
  float* pr = (float*)X;
  if (c == 0) {
#pragma unroll
    for (int mt = 0; mt < 8; ++mt)
#pragma unroll
      for (int r = 0; r < 4; ++r)
        pr[w * NT + mt * 16 + qw * 4 + r] = ll[mt][r];
  }
  __syncthreads();
  if (tid < NT) {
    float s = 0.f;
#pragma unroll
    for (int ww = 0; ww < 8; ++ww) s += pr[ww * NT + tid];
    logits[(size_t)b * ND + n0 + tid] = s;
  }
}

// K5: fused softmax + read. Grid 256 = 32 b x 8 k-tiles of 64 rows.
__global__ __launch_bounds__(256) void readsm_k(
    const float* __restrict__ know, const float* __restrict__ logits,
    float* __restrict__ out) {
  __shared__ float aw[ND];
  __shared__ float red[4];
  const int tid = threadIdx.x;
  const int wv = tid >> 6;
  const int lane = tid & 63;
  const int b = blockIdx.x >> 3;
  const int kt = blockIdx.x & 7;
  const float* l = logits + (size_t)b * ND;

  float lv[8];
  float m = -1e30f;
#pragma unroll
  for (int j = 0; j < 8; ++j) {
    lv[j] = l[tid * 8 + j];
    m = fmaxf(m, lv[j]);
  }
#pragma unroll
  for (int off = 32; off; off >>= 1) m = fmaxf(m, __shfl_xor(m, off));
  if (lane == 0) red[wv] = m;
  __syncthreads();
  float M = fmaxf(fmaxf(red[0], red[1]), fmaxf(red[2], red[3]));
  __syncthreads();
  float s = 0.f;
#pragma unroll
  for (int j = 0; j < 8; ++j) {
    float e = __expf(lv[j] - M);
    aw[tid * 8 + j] = e;
    s += e;
  }
#pragma unroll
  for (int off = 32; off; off >>= 1) s += __shfl_xor(s, off);
  if (lane == 0) red[wv] = s;
  __syncthreads();
  float invS = 1.f / (red[0] + red[1] + red[2] + red[3]);

  // 64 rows: wave wv handles rows wv*16 .. wv*16+16
  const f32x4* av = (const f32x4*)aw;
  for (int i = 0; i < 16; ++i) {
    int kk = kt * 64 + wv * 16 + i;
    const f32x4* kr = (const f32x4*)(know + ((size_t)b * HD + kk) * ND);
    float acc = 0.f;
#pragma unroll
    for (int jj = 0; jj < 8; ++jj) {
      f32x4 kv = kr[lane + 64 * jj];
      f32x4 a4 = av[lane + 64 * jj];
      acc += kv[0]*a4[0] + kv[1]*a4[1] + kv[2]*a4[2] + kv[3]*a4[3];
    }
#pragma unroll
    for (int off = 32; off; off >>= 1) acc += __shfl_xor(acc, off);
    if (lane == 0) out[(size_t)b * HD + kk] = acc * invS;
  }
}

extern "C" void kernel_launch(void* const* d_in, const int* in_sizes, int n_in,
                              void* d_out, int out_size, void* d_ws, size_t ws_size,
                              hipStream_t stream) {
  const float* memory = (const float*)d_in[0];
  const float* know = (const float*)d_in[1];
  const float* control = (const float*)d_in[2];
  const float* masks = (const float*)d_in[3];
  const float* W_mem = (const float*)d_in[4];
  const float* b_mem = (const float*)d_in[5];
  const float* W_kb = (const float*)d_in[6];
  const float* b_kb = (const float*)d_in[7];
  const float* W_cat = (const float*)d_in[8];
  const float* b_cat = (const float*)d_in[9];
  const float* W_cat2 = (const float*)d_in[10];
  const float* b_cat2 = (const float*)d_in[11];
  const float* W_attn = (const float*)d_in[12];
  // d_in[13] = b_attn: uniform logit shift, softmax-invariant.

  char* ws = (char*)d_ws;
  _Float16* Wc216 = (_Float16*)(ws);                 // 524288
  _Float16* WkbT16 = (_Float16*)(ws + 524288);       // 524288
  _Float16* W1b16 = (_Float16*)(ws + 1048576);       // 32*512*512*2 = 16777216
  float* pm = (float*)(ws + 17825792);               // 65536
  float* b1 = (float*)(ws + 17891328);               // 65536
  float* logits = (float*)(ws + 17956864);           // 262144 (total ~17.4 MB)
  float* out = (float*)d_out;

  hipLaunchKernelGGL(prep_k, dim3(160), dim3(256), 0, stream,
                     memory, masks, W_mem, b_mem, W_kb, b_kb, W_cat, b_cat,
                     W_cat2, pm, b1, Wc216, WkbT16);
  hipLaunchKernelGGL(w1gemm_k, dim3(128), dim3(512), 0, stream,
                     W_cat, pm, WkbT16, W1b16);
  hipLaunchKernelGGL(main2_k, dim3(512), dim3(512), 0, stream,
                     know, control, W1b16, Wc216, b1, b_cat2, W_attn, logits);
  hipLaunchKernelGGL(readsm_k, dim3(256), dim3(256), 0, stream,
                     know, logits, out);
}

// Round 6
// 361.233 us; speedup vs baseline: 1.3384x; 1.3384x over previous
//
#include <hip/hip_runtime.h>
#include <hip/hip_bf16.h>
#include <cmath>

#define HD 512
#define ND 2048
#define NB 32
#define NT 128   // main2: n-rows per workgroup (8 waves x 64 output cols each)

typedef _Float16 half8 __attribute__((ext_vector_type(8)));
typedef float f32x4 __attribute__((ext_vector_type(4)));

// Bank-uniform LDS layout: 16B slot for (row n, k-block kb) at
//   n*1024B + ((kb ^ q(n)) * 16B),  q(n) = (n ^ (n>>2)) & 7.
__device__ __forceinline__ int qf(int n) { return (n ^ (n >> 2)) & 7; }
__device__ __forceinline__ int xslot(int n, int kb) {
  return (n << 9) + ((kb ^ qf(n)) << 3);
}

// fast elu: for x<=0, exp(x)-1 via v_exp; abs err ~1e-6 (budget 4.5e-3)
__device__ __forceinline__ float elu_f(float x) {
  return x > 0.f ? x : __expf(x) - 1.f;
}

// K=512 GEMM stage: D[MT*16 rows][64 cols per wave] += X(MT*16 x 512,f16,LDS) * Wg^T
// mt-outer: 1 A-frag live at a time.
template <int MT>
__device__ __forceinline__ void mfma_stage_t(const _Float16* Xs,
                                             const _Float16* __restrict__ Wg,
                                             f32x4 (&acc)[MT][4], int c, int qw) {
  const _Float16* wb = Wg + (size_t)c * HD + qw * 8;
  int rowoff[MT], qn[MT];
#pragma unroll
  for (int mt = 0; mt < MT; ++mt) {
    int n = mt * 16 + c;
    rowoff[mt] = n << 9;
    qn[mt] = qf(n);
  }
#pragma unroll 2
  for (int ks = 0; ks < 16; ++ks) {
    int k8 = ks * 4 + qw;
    half8 bf[4];
#pragma unroll
    for (int ht = 0; ht < 4; ++ht)
      bf[ht] = *(const half8*)(wb + ht * (16 * HD) + ks * 32);
#pragma unroll
    for (int mt = 0; mt < MT; ++mt) {
      half8 a = *(const half8*)&Xs[rowoff[mt] + ((k8 ^ qn[mt]) << 3)];
#pragma unroll
      for (int ht = 0; ht < 4; ++ht)
        acc[mt][ht] = __builtin_amdgcn_mfma_f32_16x16x32_f16(a, bf[ht], acc[mt][ht], 0, 0, 0);
    }
  }
}

// K1 (merged): blk 0..255: pm (wave-per-h coalesced dot).
//              blk 256..319: WkbT16 64x64 tile transpose.
//              blk 320..383: Wc216 fp16 cvt.
__global__ __launch_bounds__(256) void prep0_k(
    const float* __restrict__ memory, const float* __restrict__ masks,
    const float* __restrict__ W_mem, const float* __restrict__ b_mem,
    const float* __restrict__ W_kb, const float* __restrict__ W_cat2,
    float* __restrict__ pm, _Float16* __restrict__ WkbT16,
    _Float16* __restrict__ Wc216) {
  __shared__ float smem[64 * 65];
  const int tid = threadIdx.x;
  const int blk = blockIdx.x;
  if (blk < 256) {
    // pm[b][h] = (memory[3,b,:]*masks[b,:]) . W_mem[h,:] + b_mem[h]
    int b = blk >> 3;
    int hbase = (blk & 7) * 64;
    int w = tid >> 6, lane = tid & 63;
    float* lm = smem;
    for (int i = tid; i < HD; i += 256)
      lm[i] = memory[(size_t)(3 * NB + b) * HD + i] * masks[(size_t)b * HD + i];
    __syncthreads();
    const f32x4* lmv = (const f32x4*)lm;
    f32x4 l0 = lmv[lane * 2], l1 = lmv[lane * 2 + 1];
    for (int i = 0; i < 16; ++i) {
      int h = hbase + w * 16 + i;
      const f32x4* wr = (const f32x4*)(W_mem + (size_t)h * HD);
      f32x4 w0 = wr[lane * 2], w1 = wr[lane * 2 + 1];
      float s = w0[0]*l0[0] + w0[1]*l0[1] + w0[2]*l0[2] + w0[3]*l0[3]
              + w1[0]*l1[0] + w1[1]*l1[1] + w1[2]*l1[2] + w1[3]*l1[3];
#pragma unroll
      for (int off = 32; off; off >>= 1) s += __shfl_xor(s, off);
      if (lane == 0) pm[(size_t)b * HD + h] = s + b_mem[h];
    }
  } else if (blk < 320) {
    // WkbT16[tc*64+j][tr*64+h] = (fp16) W_kb[tr*64+h][tc*64+j]
    int t = blk - 256;
    int tr = t >> 3, tc = t & 7;
    float (*tile)[65] = (float(*)[65])smem;
#pragma unroll
    for (int i = 0; i < 4; ++i) {
      int idx = i * 256 + tid;
      int r = idx >> 4;
      int c4 = (idx & 15) << 2;
      f32x4 v = *(const f32x4*)(W_kb + (size_t)(tr * 64 + r) * HD + tc * 64 + c4);
#pragma unroll
      for (int j = 0; j < 4; ++j) tile[r][c4 + j] = v[j];
    }
    __syncthreads();
    int j = tid >> 2;
    int hseg = (tid & 3) * 16;
    half8 o0, o1;
#pragma unroll
    for (int i = 0; i < 8; ++i) {
      o0[i] = (_Float16)tile[hseg + i][j];
      o1[i] = (_Float16)tile[hseg + 8 + i][j];
    }
    _Float16* dst = WkbT16 + (size_t)(tc * 64 + j) * HD + tr * 64 + hseg;
    *(half8*)dst = o0;
    *(half8*)(dst + 8) = o1;
  } else {
    // Wc216 = (fp16) W_cat2, coalesced
    int r = (blk - 320) * 8 + (tid >> 5);
    int h0 = (tid & 31) * 16;
    const float* s = W_cat2 + (size_t)r * HD + h0;
    half8 o0, o1;
#pragma unroll
    for (int j = 0; j < 4; ++j) {
      o0[j] = (_Float16)s[j];       o0[4 + j] = (_Float16)s[4 + j];
      o1[j] = (_Float16)s[8 + j];   o1[4 + j] = (_Float16)s[12 + j];
    }
    *(half8*)(Wc216 + (size_t)r * HD + h0) = o0;
    *(half8*)(Wc216 + (size_t)r * HD + h0 + 8) = o1;
  }
}

// K2: W1b[b] = Weff_b @ W_kb, where Weff_b[r][h] = pm[b][h]*W_cat[r][h] + W_cat[r][512+h].
// Also emits b1[b][r] = Weff_b[r,:] . b_kb + b_cat[r] from the LDS A-tile.
// Grid 256 = 32 b x 8 row-tiles of 64. 8 waves x 64 j-cols.
__global__ __launch_bounds__(512, 2) void w1gemm_k(
    const float* __restrict__ W_cat, const float* __restrict__ pm,
    const float* __restrict__ b_kb, const float* __restrict__ b_cat,
    const _Float16* __restrict__ WkbT16,
    _Float16* __restrict__ W1b16, float* __restrict__ b1) {
  __shared__ _Float16 A[64 * HD];   // 64 KB
  __shared__ float pms[HD];
  const int tid = threadIdx.x;
  const int w = tid >> 6;
  const int lane = tid & 63;
  const int c = lane & 15;
  const int qw = lane >> 4;
  const int b = blockIdx.x >> 3;
  const int r0 = (blockIdx.x & 7) * 64;

  if (tid < HD) pms[tid] = pm[(size_t)b * HD + tid];
  __syncthreads();

  // A[r][h] = (fp16)(pms[h]*W_cat[r0+r][h] + W_cat[r0+r][512+h]); coalesced reads.
#pragma unroll 2
  for (int it = 0; it < 8; ++it) {
    int u = it * 512 + tid;
    int kb = u & 63;
    int r = u >> 6;
    const float* wc = W_cat + (size_t)(r0 + r) * (2 * HD) + kb * 8;
    f32x4 a0 = *(const f32x4*)wc;
    f32x4 a1 = *(const f32x4*)(wc + 4);
    f32x4 c0 = *(const f32x4*)(wc + HD);
    f32x4 c1 = *(const f32x4*)(wc + HD + 4);
    f32x4 p0 = *(const f32x4*)(pms + kb * 8);
    f32x4 p1 = *(const f32x4*)(pms + kb * 8 + 4);
    half8 hv;
#pragma unroll
    for (int j = 0; j < 4; ++j) {
      hv[j]     = (_Float16)(p0[j] * a0[j] + c0[j]);
      hv[4 + j] = (_Float16)(p1[j] * a1[j] + c1[j]);
    }
    *(half8*)&A[xslot(r, kb)] = hv;
  }
  __syncthreads();

  f32x4 acc[4][4];
  const f32x4 z4 = {0.f, 0.f, 0.f, 0.f};
#pragma unroll
  for (int mt = 0; mt < 4; ++mt)
#pragma unroll
    for (int ht = 0; ht < 4; ++ht) acc[mt][ht] = z4;
  mfma_stage_t<4>(A, WkbT16 + (size_t)(w * 64) * HD, acc, c, qw);

  // b1 from LDS A-tile: wave w owns rows w*8..w*8+8; lanes stride kb (coalesced).
  {
    const f32x4* bk = (const f32x4*)(b_kb + lane * 8);
    f32x4 b0 = bk[0], b1v = bk[1];
#pragma unroll 2
    for (int i = 0; i < 8; ++i) {
      int r = w * 8 + i;
      half8 av = *(const half8*)&A[xslot(r, lane)];
      float s = (float)av[0]*b0[0] + (float)av[1]*b0[1] + (float)av[2]*b0[2] + (float)av[3]*b0[3]
              + (float)av[4]*b1v[0] + (float)av[5]*b1v[1] + (float)av[6]*b1v[2] + (float)av[7]*b1v[3];
#pragma unroll
      for (int off = 32; off; off >>= 1) s += __shfl_xor(s, off);
      if (lane == 0) b1[(size_t)b * HD + r0 + r] = s + b_cat[r0 + r];
    }
  }

  // epilogue: W1b16[b][r0+row][col]
#pragma unroll
  for (int ht = 0; ht < 4; ++ht) {
    int col = w * 64 + ht * 16 + c;
#pragma unroll
    for (int mt = 0; mt < 4; ++mt)
#pragma unroll
      for (int r = 0; r < 4; ++r)
        W1b16[((size_t)b * HD + r0 + mt * 16 + qw * 4 + r) * HD + col] =
            (_Float16)acc[mt][ht][r];
  }
}

// K3: fused 2-stage chain + logits. XCD-swizzled grid: each b's 16 wgs on one XCD.
__global__ __launch_bounds__(512, 2) void main2_k(
    const float* __restrict__ know, const float* __restrict__ control,
    const _Float16* __restrict__ W1b16, const _Float16* __restrict__ Wc216,
    const float* __restrict__ b1, const float* __restrict__ b_cat2,
    const float* __restrict__ W_attn, float* __restrict__ logits) {
  __shared__ _Float16 X[NT * HD];   // 128 KB
  const int tid = threadIdx.x;
  const int w = tid >> 6;
  const int lane = tid & 63;
  const int c = lane & 15;
  const int qw = lane >> 4;
  const int gid = blockIdx.x;
  const int slot = gid >> 3;
  const int b = ((gid & 7) << 2) + (slot >> 4);   // 4 b per XCD -> W1b_b L2-resident
  const int n0 = (slot & 15) * NT;

  // stage 0: transpose know[b][k][n0+n] -> X (fp16), full half8 LDS writes.
  {
    const float* kptr = know + (size_t)b * HD * ND + n0;
#pragma unroll
    for (int it = 0; it < 4; ++it) {
      int u = it * 512 + tid;
      int n4 = (u & 31) << 2;
      int kb = u >> 5;
      int k0 = kb << 3;
      f32x4 v[8];
#pragma unroll
      for (int kk = 0; kk < 8; ++kk)
        v[kk] = *(const f32x4*)(kptr + (size_t)(k0 + kk) * ND + n4);
#pragma unroll
      for (int j = 0; j < 4; ++j) {
        int n = n4 + j;
        half8 hv;
#pragma unroll
        for (int kk = 0; kk < 8; ++kk) hv[kk] = (_Float16)v[kk][j];
        *(half8*)&X[xslot(n, kb)] = hv;
      }
    }
  }
  __syncthreads();

  f32x4 acc[8][4];
  const f32x4 z4 = {0.f, 0.f, 0.f, 0.f};

  // ---- stage A: h = elu(know_tile . W1b_b^T + b1_b)
#pragma unroll
  for (int mt = 0; mt < 8; ++mt)
#pragma unroll
    for (int ht = 0; ht < 4; ++ht) acc[mt][ht] = z4;
  mfma_stage_t<8>(X, W1b16 + ((size_t)b * HD + w * 64) * HD, acc, c, qw);
  __syncthreads();
#pragma unroll
  for (int ht = 0; ht < 4; ++ht) {
    int col = w * 64 + ht * 16 + c;
    float bias = b1[(size_t)b * HD + col];
    int kb = col >> 3, k7 = col & 7;
#pragma unroll
    for (int mt = 0; mt < 8; ++mt)
#pragma unroll
      for (int r = 0; r < 4; ++r) {
        float v = elu_f(acc[mt][ht][r] + bias);
        int n = mt * 16 + qw * 4 + r;
        X[xslot(n, kb) + k7] = (_Float16)v;
      }
  }
  __syncthreads();

  // ---- stage B: h2 = h . Wc2^T + b_cat2; attn = elu(h2*ctl); logits = attn . W_attn
#pragma unroll
  for (int mt = 0; mt < 8; ++mt)
#pragma unroll
    for (int ht = 0; ht < 4; ++ht) acc[mt][ht] = z4;
  mfma_stage_t<8>(X, Wc216 + (size_t)(w * 64) * HD, acc, c, qw);

  float ll[8][4];
#pragma unroll
  for (int mt = 0; mt < 8; ++mt)
#pragma unroll
    for (int r = 0; r < 4; ++r) ll[mt][r] = 0.f;
  const float* ctl = control + (size_t)(3 * NB + b) * HD;
#pragma unroll
  for (int ht = 0; ht < 4; ++ht) {
    int col = w * 64 + ht * 16 + c;
    float bias = b_cat2[col];
    float cv = ctl[col];
    float wa = W_attn[col];
#pragma unroll
    for (int mt = 0; mt < 8; ++mt)
#pragma unroll
      for (int r = 0; r < 4; ++r) {
        float at = elu_f((acc[mt][ht][r] + bias) * cv);
        ll[mt][r] += at * wa;
      }
  }
#pragma unroll
  for (int off = 1; off <= 8; off <<= 1)
#pragma unroll
    for (int mt = 0; mt < 8; ++mt)
#pragma unroll
      for (int r = 0; r < 4; ++r) ll[mt][r] += __shfl_xor(ll[mt][r], off);

  __syncthreads();
  float* pr = (float*)X;
  if (c == 0) {
#pragma unroll
    for (int mt = 0; mt < 8; ++mt)
#pragma unroll
      for (int r = 0; r < 4; ++r)
        pr[w * NT + mt * 16 + qw * 4 + r] = ll[mt][r];
  }
  __syncthreads();
  if (tid < NT) {
    float s = 0.f;
#pragma unroll
    for (int ww = 0; ww < 8; ++ww) s += pr[ww * NT + tid];
    logits[(size_t)b * ND + n0 + tid] = s;
  }
}

// K4: fused softmax + read. Grid 256 = 32 b x 8 k-tiles of 64 rows.
__global__ __launch_bounds__(256) void readsm_k(
    const float* __restrict__ know, const float* __restrict__ logits,
    float* __restrict__ out) {
  __shared__ float aw[ND];
  __shared__ float red[4];
  const int tid = threadIdx.x;
  const int wv = tid >> 6;
  const int lane = tid & 63;
  const int b = blockIdx.x >> 3;
  const int kt = blockIdx.x & 7;
  const float* l = logits + (size_t)b * ND;

  float lv[8];
  float m = -1e30f;
#pragma unroll
  for (int j = 0; j < 8; ++j) {
    lv[j] = l[tid * 8 + j];
    m = fmaxf(m, lv[j]);
  }
#pragma unroll
  for (int off = 32; off; off >>= 1) m = fmaxf(m, __shfl_xor(m, off));
  if (lane == 0) red[wv] = m;
  __syncthreads();
  float M = fmaxf(fmaxf(red[0], red[1]), fmaxf(red[2], red[3]));
  __syncthreads();
  float s = 0.f;
#pragma unroll
  for (int j = 0; j < 8; ++j) {
    float e = __expf(lv[j] - M);
    aw[tid * 8 + j] = e;
    s += e;
  }
#pragma unroll
  for (int off = 32; off; off >>= 1) s += __shfl_xor(s, off);
  if (lane == 0) red[wv] = s;
  __syncthreads();
  float invS = 1.f / (red[0] + red[1] + red[2] + red[3]);

  const f32x4* av = (const f32x4*)aw;
  for (int i = 0; i < 16; ++i) {
    int kk = kt * 64 + wv * 16 + i;
    const f32x4* kr = (const f32x4*)(know + ((size_t)b * HD + kk) * ND);
    float acc = 0.f;
#pragma unroll
    for (int jj = 0; jj < 8; ++jj) {
      f32x4 kv = kr[lane + 64 * jj];
      f32x4 a4 = av[lane + 64 * jj];
      acc += kv[0]*a4[0] + kv[1]*a4[1] + kv[2]*a4[2] + kv[3]*a4[3];
    }
#pragma unroll
    for (int off = 32; off; off >>= 1) acc += __shfl_xor(acc, off);
    if (lane == 0) out[(size_t)b * HD + kk] = acc * invS;
  }
}

extern "C" void kernel_launch(void* const* d_in, const int* in_sizes, int n_in,
                              void* d_out, int out_size, void* d_ws, size_t ws_size,
                              hipStream_t stream) {
  const float* memory = (const float*)d_in[0];
  const float* know = (const float*)d_in[1];
  const float* control = (const float*)d_in[2];
  const float* masks = (const float*)d_in[3];
  const float* W_mem = (const float*)d_in[4];
  const float* b_mem = (const float*)d_in[5];
  const float* W_kb = (const float*)d_in[6];
  const float* b_kb = (const float*)d_in[7];
  const float* W_cat = (const float*)d_in[8];
  const float* b_cat = (const float*)d_in[9];
  const float* W_cat2 = (const float*)d_in[10];
  const float* b_cat2 = (const float*)d_in[11];
  const float* W_attn = (const float*)d_in[12];
  // d_in[13] = b_attn: uniform logit shift, softmax-invariant.

  char* ws = (char*)d_ws;
  _Float16* Wc216 = (_Float16*)(ws);                 // 524288
  _Float16* WkbT16 = (_Float16*)(ws + 524288);       // 524288
  _Float16* W1b16 = (_Float16*)(ws + 1048576);       // 16777216
  float* pm = (float*)(ws + 17825792);               // 65536
  float* b1 = (float*)(ws + 17891328);               // 65536
  float* logits = (float*)(ws + 17956864);           // 262144
  float* out = (float*)d_out;

  hipLaunchKernelGGL(prep0_k, dim3(384), dim3(256), 0, stream,
                     memory, masks, W_mem, b_mem, W_kb, W_cat2,
                     pm, WkbT16, Wc216);
  hipLaunchKernelGGL(w1gemm_k, dim3(256), dim3(512), 0, stream,
                     W_cat, pm, b_kb, b_cat, WkbT16, W1b16, b1);
  hipLaunchKernelGGL(main2_k, dim3(512), dim3(512), 0, stream,
                     know, control, W1b16, Wc216, b1, b_cat2, W_attn, logits);
  hipLaunchKernelGGL(readsm_k, dim3(256), dim3(256), 0, stream,
                     know, logits, out);
}